// Round 2
// baseline (91.271 us; speedup 1.0000x reference)
//
#include <hip/hip_runtime.h>

#define NN 8
#define HH 512
#define WW 512
#define CC 3
#define KK 5
#define PADP 2
#define BLK 256                   // pixels per block (contiguous along W)
#define TILE_W (BLK + KK - 1)     // 260
#define ROW3 (TILE_W * CC)        // 780 floats per tile row
#define IN_TILE (KK * ROW3)       // 3900 floats
#define W_TILE (BLK * KK * KK)    // 6400 floats

__global__ __launch_bounds__(256) void conv_local_kernel(
    const float* __restrict__ in,   // (N,H,W,C)
    const float* __restrict__ wt,   // (N,H,W,25)
    float* __restrict__ out)        // (N,H,W,C)
{
    __shared__ float w_lds[W_TILE];    // 25.6 KB
    __shared__ float in_lds[IN_TILE];  // 15.6 KB

    const int tid = threadIdx.x;
    const int blk = blockIdx.x;            // 0..8191
    // 2 blocks per row, 512 rows per image, 8 images
    const int wseg = blk & 1;
    const int h    = (blk >> 1) & (HH - 1);
    const int n    = blk >> 10;
    const int w0   = wseg * BLK;
    const long pix0 = ((long)n * HH + h) * WW + w0;   // first pixel of block

    // --- stage weights: 6400 dwords, fully coalesced (stride-1 across lanes) ---
    const float* wsrc = wt + pix0 * (KK * KK);
#pragma unroll
    for (int it = 0; it < KK * KK; ++it)
        w_lds[it * BLK + tid] = wsrc[it * BLK + tid];

    // --- stage input halo tile (5 rows x 260 px x 3 ch), zero-padded, coalesced ---
    const float* inb = in + (long)n * (HH * WW * CC);
    for (int idx = tid; idx < IN_TILE; idx += BLK) {
        int r  = idx / ROW3;          // tile row 0..4   (magic-mul)
        int c3 = idx - r * ROW3;      // 0..779
        int pc = c3 / 3;              // tile pixel col 0..259
        int ch = c3 - pc * 3;
        int gh = h + r - PADP;
        int gw = w0 + pc - PADP;
        float v = 0.f;
        if ((unsigned)gh < (unsigned)HH && (unsigned)gw < (unsigned)WW)
            v = inb[((long)gh * WW + gw) * CC + ch];
        in_lds[idx] = v;
    }
    __syncthreads();

    // --- compute: 25 taps x 3 channels from LDS ---
    float acc0 = 0.f, acc1 = 0.f, acc2 = 0.f;
    const float* wp = &w_lds[tid * (KK * KK)];
#pragma unroll
    for (int dh = 0; dh < KK; ++dh) {
        const int rb = dh * ROW3 + tid * CC;
#pragma unroll
        for (int dw = 0; dw < KK; ++dw) {
            const float wv = wp[dh * KK + dw];
            const int o = rb + dw * CC;
            acc0 = fmaf(in_lds[o + 0], wv, acc0);
            acc1 = fmaf(in_lds[o + 1], wv, acc1);
            acc2 = fmaf(in_lds[o + 2], wv, acc2);
        }
    }

    float* op = out + (pix0 + tid) * CC;
    op[0] = acc0;
    op[1] = acc1;
    op[2] = acc2;
}

extern "C" void kernel_launch(void* const* d_in, const int* in_sizes, int n_in,
                              void* d_out, int out_size, void* d_ws, size_t ws_size,
                              hipStream_t stream) {
    const float* in = (const float*)d_in[0];   // (8,512,512,3) f32
    const float* wt = (const float*)d_in[1];   // (8,512,512,25) f32
    float* out = (float*)d_out;                // (8,512,512,3) f32

    const int grid = NN * HH * (WW / BLK);     // 8192 blocks
    conv_local_kernel<<<grid, BLK, 0, stream>>>(in, wt, out);
}